// Round 1
// baseline (738.066 us; speedup 1.0000x reference)
//
#include <hip/hip_runtime.h>
#include <cstdint>

// TypedTreeCell reduce: per-type TreeLSTM child aggregation.
// N=65536 nodes, K=8 children, H=128, T=4 types.
// out[n] = concat( h_sum[n] @ U_iou[t] + b_iou[t],
//                  sum_k sigmoid(f_input[n] + h[n,k] @ U_f[t] + b_f[t]) * c[n,k] )
//
// Strategy: bucket nodes by type on device (ballot-aggregated counting sort),
// then per (type, 16-node tile) run bf16 MFMA GEMMs with U pre-swizzled into
// B-fragment order (read straight from global/L2, no LDS for B).

typedef __bf16 bf16;
typedef bf16 bf16x8 __attribute__((ext_vector_type(8)));
typedef float f32x4 __attribute__((ext_vector_type(4)));

#define N_NODES 65536
#define KCH 8
#define HSZ 128
#define T_TYPES 4
#define TM 16            // nodes per tile
#define LDS_STRIDE 136   // bf16 elems per LDS row (128 + 8 pad -> 2-way banks, free)

// ---------------- workspace layout ----------------
// [0..15]   counts[4]
// [16..31]  cursors[4]
// [32..47]  offsets[4]
// [256 .. 256+262144)           perm (N int32)
// [+0 .. 131072)                preUf  (4*128*128 bf16, B-fragment order)
// [+131072 .. +524288)          preUiou (4*128*384 bf16, B-fragment order)
#define WS_PERM_OFF   256
#define WS_PREUF_OFF  (WS_PERM_OFF + 4*N_NODES)
#define WS_PREUIOU_OFF (WS_PREUF_OFF + 131072)

// ---------------- type histogram ----------------
__global__ void k_count(const int* __restrict__ ta, int* __restrict__ ws_i) {
    int i = blockIdx.x * blockDim.x + threadIdx.x;
    int t = ta[i];
    int lane = threadIdx.x & 63;
    #pragma unroll
    for (int tt = 0; tt < T_TYPES; ++tt) {
        unsigned long long m = __ballot(t == tt);
        int leader = __ffsll((unsigned long long)m) - 1;
        if (t == tt && lane == leader)
            atomicAdd(&ws_i[tt], (int)__popcll(m));
    }
}

__global__ void k_offsets(int* ws_i) {
    if (threadIdx.x == 0 && blockIdx.x == 0) {
        int acc = 0;
        for (int t = 0; t < T_TYPES; ++t) {
            ws_i[8 + t] = acc;   // offsets
            ws_i[4 + t] = acc;   // cursors
            acc += ws_i[t];
        }
    }
}

__global__ void k_scatter(const int* __restrict__ ta, int* __restrict__ ws_i,
                          int* __restrict__ perm) {
    int i = blockIdx.x * blockDim.x + threadIdx.x;
    int t = ta[i];
    int lane = threadIdx.x & 63;
    #pragma unroll
    for (int tt = 0; tt < T_TYPES; ++tt) {
        unsigned long long m = __ballot(t == tt);
        if (t == tt) {
            int leader = __ffsll((unsigned long long)m) - 1;
            int base = 0;
            if (lane == leader) base = atomicAdd(&ws_i[4 + tt], (int)__popcll(m));
            base = __shfl(base, leader, 64);
            int rank = (int)__popcll(m & ((1ull << lane) - 1ull));
            perm[base + rank] = i;
        }
    }
}

// ---------------- U pre-swizzle into MFMA-B fragment order ----------------
// B frag for 16x16x32 bf16: lane l holds B[k = kblk*32 + (l>>4)*8 + e][col = colblk*16 + (l&15)]
// stored as [t][kblk][colblk][lane][e] bf16 -> each fragment is one coalesced 16B load.
__global__ void k_swz_uf(const float* __restrict__ U, bf16* __restrict__ dst) {
    int idx = blockIdx.x * blockDim.x + threadIdx.x;      // < 4*128*128
    int t = idx >> 14;
    int r = (idx >> 7) & 127;   // k index
    int j = idx & 127;          // col
    float v = U[idx];
    int kblk = r >> 5, kin = r & 31;
    int lane = ((kin >> 3) << 4) | (j & 15);
    int e = kin & 7;
    int cb = j >> 4;            // 8 col blocks
    dst[((((t * 4 + kblk) * 8 + cb) * 64 + lane) << 3) + e] = (bf16)v;
}

__global__ void k_swz_uiou(const float* __restrict__ U, bf16* __restrict__ dst) {
    int idx = blockIdx.x * blockDim.x + threadIdx.x;      // < 4*128*384
    int t = idx / 49152;
    int rm = idx - t * 49152;
    int r = rm / 384;
    int j = rm - r * 384;
    float v = U[idx];
    int kblk = r >> 5, kin = r & 31;
    int lane = ((kin >> 3) << 4) | (j & 15);
    int e = kin & 7;
    int cb = j >> 4;            // 24 col blocks
    dst[((((t * 4 + kblk) * 24 + cb) * 64 + lane) << 3) + e] = (bf16)v;
}

// ---------------- main fused kernel ----------------
__global__ __launch_bounds__(256, 2) void k_main(
    const float* __restrict__ h, const float* __restrict__ c,
    const float* __restrict__ f_input,
    const float* __restrict__ b_iou, const float* __restrict__ b_f,
    const int* __restrict__ perm, const int* __restrict__ ws_i,
    const bf16* __restrict__ preUf, const bf16* __restrict__ preUiou,
    float* __restrict__ out)
{
    const int t = blockIdx.y;
    const int tile = blockIdx.x;
    const int cnt = ws_i[t];
    if (tile * TM >= cnt) return;
    const int base = ws_i[8 + t] + tile * TM;
    const int rem = min(TM, cnt - tile * TM);

    // LDS: 128 child rows + 16 h_sum rows, bf16, padded stride
    __shared__ __align__(16) bf16 hs[(128 + 16) * LDS_STRIDE];
    bf16* hsum = hs + 128 * LDS_STRIDE;

    const int tid = threadIdx.x;
    const int w = tid >> 6;        // wave 0..3
    const int l = tid & 63;        // lane
    const int lu = l & 15;
    const int g = l >> 4;          // quad group 0..3

    // ---- stage h as bf16 into LDS; accumulate per-lane h_sum (8 cols) ----
    {
        int mloc = w * 4 + g;                       // node-in-tile 0..15
        int mc = mloc < rem ? mloc : 0;             // clamp pad rows to node 0 (real data)
        long gn = perm[base + mc];
        const float* hp = h + gn * (long)(KCH * HSZ) + lu * 8;
        float sarr[8];
        #pragma unroll
        for (int i = 0; i < 8; ++i) sarr[i] = 0.f;
        #pragma unroll
        for (int k = 0; k < KCH; ++k) {
            const float4* p = (const float4*)(hp + k * HSZ);
            float4 a = p[0], b = p[1];
            sarr[0] += a.x; sarr[1] += a.y; sarr[2] += a.z; sarr[3] += a.w;
            sarr[4] += b.x; sarr[5] += b.y; sarr[6] += b.z; sarr[7] += b.w;
            bf16x8 v;
            v[0] = (bf16)a.x; v[1] = (bf16)a.y; v[2] = (bf16)a.z; v[3] = (bf16)a.w;
            v[4] = (bf16)b.x; v[5] = (bf16)b.y; v[6] = (bf16)b.z; v[7] = (bf16)b.w;
            *((bf16x8*)&hs[(mloc * KCH + k) * LDS_STRIDE + lu * 8]) = v;
        }
        bf16x8 sv;
        #pragma unroll
        for (int i = 0; i < 8; ++i) sv[i] = (bf16)sarr[i];
        *((bf16x8*)&hsum[mloc * LDS_STRIDE + lu * 8]) = sv;
    }
    __syncthreads();

    // ---- f-gate GEMM: [128 child rows, 128] @ U_f[t] (col-split across waves) ----
    f32x4 acc[8][2];
    #pragma unroll
    for (int rt = 0; rt < 8; ++rt)
        #pragma unroll
        for (int cb = 0; cb < 2; ++cb)
            acc[rt][cb] = (f32x4){0.f, 0.f, 0.f, 0.f};

    const bf16x8* Bf = (const bf16x8*)preUf;
    #pragma unroll
    for (int kb = 0; kb < 4; ++kb) {
        bf16x8 b0 = Bf[((t * 4 + kb) * 8 + w * 2 + 0) * 64 + l];
        bf16x8 b1 = Bf[((t * 4 + kb) * 8 + w * 2 + 1) * 64 + l];
        #pragma unroll
        for (int rt = 0; rt < 8; ++rt) {
            bf16x8 a = *((const bf16x8*)&hs[(rt * 16 + lu) * LDS_STRIDE + kb * 32 + g * 8]);
            acc[rt][0] = __builtin_amdgcn_mfma_f32_16x16x32_bf16(a, b0, acc[rt][0], 0, 0, 0);
            acc[rt][1] = __builtin_amdgcn_mfma_f32_16x16x32_bf16(a, b1, acc[rt][1], 0, 0, 0);
        }
    }

    // ---- f epilogue: sigmoid, *c, reduce 8 children -> c_aggr ----
    // C/D layout: col = lane&15, row = (lane>>4)*4 + reg.
    // f-row = m*8 + k; row-tile rt covers nodes rt*2 + (g>>1), k = (g&1)*4 + reg.
    {
        const int col0 = w * 32 + lu;
        const float bf0 = b_f[t * HSZ + col0];
        const float bf1 = b_f[t * HSZ + col0 + 16];
        #pragma unroll
        for (int rt = 0; rt < 8; ++rt) {
            int m = rt * 2 + (g >> 1);
            int mc = m < rem ? m : 0;
            long gn = perm[base + mc];
            #pragma unroll
            for (int cb = 0; cb < 2; ++cb) {
                int col = col0 + cb * 16;
                float fiv = f_input[gn * HSZ + col];
                float bfv = cb ? bf1 : bf0;
                float p = 0.f;
                #pragma unroll
                for (int r = 0; r < 4; ++r) {
                    int k = ((g & 1) << 2) + r;
                    float s = acc[rt][cb][r] + fiv + bfv;
                    float fg = 1.0f / (1.0f + __expf(-s));
                    float cv = c[(gn * KCH + k) * HSZ + col];
                    p += fg * cv;
                }
                p += __shfl_xor(p, 16, 64);   // combine k=0..3 with k=4..7 halves
                if (((g & 1) == 0) && m < rem)
                    out[gn * (4 * HSZ) + 3 * HSZ + col] = p;
            }
        }
    }

    // ---- iou GEMM: [16, 128] @ U_iou[t] [128, 384] ----
    f32x4 acc2[6];
    #pragma unroll
    for (int cf = 0; cf < 6; ++cf) acc2[cf] = (f32x4){0.f, 0.f, 0.f, 0.f};
    const bf16x8* Bi = (const bf16x8*)preUiou;
    #pragma unroll
    for (int kb = 0; kb < 4; ++kb) {
        bf16x8 a = *((const bf16x8*)&hsum[lu * LDS_STRIDE + kb * 32 + g * 8]);
        #pragma unroll
        for (int cf = 0; cf < 6; ++cf) {
            bf16x8 b = Bi[((t * 4 + kb) * 24 + w * 6 + cf) * 64 + l];
            acc2[cf] = __builtin_amdgcn_mfma_f32_16x16x32_bf16(a, b, acc2[cf], 0, 0, 0);
        }
    }
    // iou epilogue: row m = g*4 + reg
    {
        long gns[4]; bool ok[4];
        #pragma unroll
        for (int r = 0; r < 4; ++r) {
            int m = g * 4 + r;
            ok[r] = m < rem;
            gns[r] = perm[base + (ok[r] ? m : 0)];
        }
        #pragma unroll
        for (int cf = 0; cf < 6; ++cf) {
            int col = w * 96 + cf * 16 + lu;
            float bi = b_iou[t * 384 + col];
            #pragma unroll
            for (int r = 0; r < 4; ++r)
                if (ok[r]) out[gns[r] * (4 * HSZ) + col] = acc2[cf][r] + bi;
        }
    }
}

extern "C" void kernel_launch(void* const* d_in, const int* in_sizes, int n_in,
                              void* d_out, int out_size, void* d_ws, size_t ws_size,
                              hipStream_t stream) {
    const float* h       = (const float*)d_in[0];
    const float* c       = (const float*)d_in[1];
    const float* f_input = (const float*)d_in[2];
    const int*   type_id = (const int*)d_in[3];
    const float* U_iou   = (const float*)d_in[4];
    const float* b_iou   = (const float*)d_in[5];
    const float* U_f     = (const float*)d_in[6];
    const float* b_f     = (const float*)d_in[7];
    float* out = (float*)d_out;

    char* ws = (char*)d_ws;
    int* ws_i = (int*)ws;
    int* perm = (int*)(ws + WS_PERM_OFF);
    bf16* preUf = (bf16*)(ws + WS_PREUF_OFF);
    bf16* preUiou = (bf16*)(ws + WS_PREUIOU_OFF);

    hipMemsetAsync(ws, 0, 64, stream);
    k_swz_uf  <<<(T_TYPES * HSZ * HSZ) / 256, 256, 0, stream>>>(U_f, preUf);
    k_swz_uiou<<<(T_TYPES * HSZ * 3 * HSZ) / 256, 256, 0, stream>>>(U_iou, preUiou);
    k_count   <<<N_NODES / 256, 256, 0, stream>>>(type_id, ws_i);
    k_offsets <<<1, 64, 0, stream>>>(ws_i);
    k_scatter <<<N_NODES / 256, 256, 0, stream>>>(type_id, ws_i, perm);

    dim3 grid(N_NODES / TM, T_TYPES);
    k_main<<<grid, 256, 0, stream>>>(h, c, f_input, b_iou, b_f,
                                     perm, ws_i, preUf, preUiou, out);
}

// Round 2
// 708.799 us; speedup vs baseline: 1.0413x; 1.0413x over previous
//
#include <hip/hip_runtime.h>
#include <cstdint>

// TypedTreeCell reduce: per-type TreeLSTM child aggregation.
// N=65536 nodes, K=8 children, H=128, T=4 types.
// out[n] = concat( h_sum[n] @ U_iou[t] + b_iou[t],
//                  sum_k sigmoid(f_input[n] + h[n,k] @ U_f[t] + b_f[t]) * c[n,k] )
//
// R2: 512-thread blocks (halve per-lane MFMA accumulators -> occupancy),
// f-gate pre-activations round-trip through LDS so the c-reduction pass
// reads c/f_input as coalesced float4; flat tile index (no early-exit blocks).

typedef __bf16 bf16;
typedef bf16 bf16x8 __attribute__((ext_vector_type(8)));
typedef bf16 bf16x4 __attribute__((ext_vector_type(4)));
typedef float f32x4 __attribute__((ext_vector_type(4)));

#define N_NODES 65536
#define KCH 8
#define HSZ 128
#define T_TYPES 4
#define TM 16            // nodes per tile
#define LDS_STRIDE 136   // bf16 elems per LDS row (128 + 8 pad)

// ---------------- workspace layout ----------------
// ints: [0..3] counts, [4..7] cursors, [8..11] node offsets,
//       [12..15] tile offsets, [16] total tiles
#define WS_PERM_OFF   256
#define WS_PREUF_OFF  (WS_PERM_OFF + 4*N_NODES)
#define WS_PREUIOU_OFF (WS_PREUF_OFF + 131072)

// ---------------- type histogram ----------------
__global__ void k_count(const int* __restrict__ ta, int* __restrict__ ws_i) {
    int i = blockIdx.x * blockDim.x + threadIdx.x;
    int t = ta[i];
    int lane = threadIdx.x & 63;
    #pragma unroll
    for (int tt = 0; tt < T_TYPES; ++tt) {
        unsigned long long m = __ballot(t == tt);
        int leader = __ffsll((unsigned long long)m) - 1;
        if (t == tt && lane == leader)
            atomicAdd(&ws_i[tt], (int)__popcll(m));
    }
}

__global__ void k_offsets(int* ws_i) {
    if (threadIdx.x == 0 && blockIdx.x == 0) {
        int acc = 0, tacc = 0;
        for (int t = 0; t < T_TYPES; ++t) {
            int cnt = ws_i[t];
            ws_i[8 + t] = acc;    // node offset
            ws_i[4 + t] = acc;    // cursor
            ws_i[12 + t] = tacc;  // tile offset
            acc += cnt;
            tacc += (cnt + TM - 1) / TM;
        }
        ws_i[16] = tacc;
    }
}

__global__ void k_scatter(const int* __restrict__ ta, int* __restrict__ ws_i,
                          int* __restrict__ perm) {
    int i = blockIdx.x * blockDim.x + threadIdx.x;
    int t = ta[i];
    int lane = threadIdx.x & 63;
    #pragma unroll
    for (int tt = 0; tt < T_TYPES; ++tt) {
        unsigned long long m = __ballot(t == tt);
        if (t == tt) {
            int leader = __ffsll((unsigned long long)m) - 1;
            int base = 0;
            if (lane == leader) base = atomicAdd(&ws_i[4 + tt], (int)__popcll(m));
            base = __shfl(base, leader, 64);
            int rank = (int)__popcll(m & ((1ull << lane) - 1ull));
            perm[base + rank] = i;
        }
    }
}

// ---------------- U pre-swizzle into MFMA-B fragment order ----------------
// B frag for 16x16x32 bf16: lane l holds B[k = kblk*32 + (l>>4)*8 + e][col = cb*16 + (l&15)]
// stored as [t][kblk][colblk][lane][e] -> each fragment is one coalesced 16B load.
__global__ void k_swz(const float* __restrict__ Uf, const float* __restrict__ Uiou,
                      bf16* __restrict__ dstf, bf16* __restrict__ dstiou) {
    int idx = blockIdx.x * blockDim.x + threadIdx.x;   // < 262144
    if (idx < T_TYPES * HSZ * HSZ) {
        int t = idx >> 14;
        int r = (idx >> 7) & 127;
        int j = idx & 127;
        float v = Uf[idx];
        int kblk = r >> 5, kin = r & 31;
        int lane = ((kin >> 3) << 4) | (j & 15);
        int e = kin & 7;
        int cb = j >> 4;
        dstf[((((t * 4 + kblk) * 8 + cb) * 64 + lane) << 3) + e] = (bf16)v;
    } else {
        int i2 = idx - T_TYPES * HSZ * HSZ;            // < 4*128*384
        int t = i2 / 49152;
        int rm = i2 - t * 49152;
        int r = rm / 384;
        int j = rm - r * 384;
        float v = Uiou[i2];
        int kblk = r >> 5, kin = r & 31;
        int lane = ((kin >> 3) << 4) | (j & 15);
        int e = kin & 7;
        int cb = j >> 4;
        dstiou[((((t * 4 + kblk) * 24 + cb) * 64 + lane) << 3) + e] = (bf16)v;
    }
}

// ---------------- main fused kernel (512 threads / 16-node tile) ----------------
__global__ __launch_bounds__(512, 4) void k_main(
    const float* __restrict__ h, const float* __restrict__ c,
    const float* __restrict__ f_input,
    const float* __restrict__ b_iou, const float* __restrict__ b_f,
    const int* __restrict__ perm, const int* __restrict__ ws_i,
    const bf16* __restrict__ preUf, const bf16* __restrict__ preUiou,
    float* __restrict__ out)
{
    const int b = blockIdx.x;
    if (b >= ws_i[16]) return;
    int t;
    if (b < ws_i[13]) t = 0;
    else if (b < ws_i[14]) t = 1;
    else if (b < ws_i[15]) t = 2;
    else t = 3;
    const int tile = b - ws_i[12 + t];
    const int cnt = ws_i[t];
    const int base = ws_i[8 + t] + tile * TM;
    const int rem = min(TM, cnt - tile * TM);

    // LDS: 128 child rows (reused later for f-gate pre-acts) + 16 h_sum rows
    __shared__ __align__(16) bf16 hs[(128 + 16) * LDS_STRIDE];
    bf16* hsum = hs + 128 * LDS_STRIDE;

    const int tid = threadIdx.x;
    const int w2 = tid >> 6;       // wave 0..7
    const int l = tid & 63;
    const int lu = l & 15;
    const int g = l >> 4;          // quad group 0..3

    // ---- stage h as bf16 into LDS; per-lane partial h_sum over 4 children ----
    {
        int node = w2 * 2 + (g >> 1);               // node-in-tile 0..15
        int khalf = (g & 1) * 4;
        int mc = node < rem ? node : 0;
        long gn = perm[base + mc];
        const float* hp = h + gn * (long)(KCH * HSZ) + lu * 8;
        float sarr[8];
        #pragma unroll
        for (int i = 0; i < 8; ++i) sarr[i] = 0.f;
        #pragma unroll
        for (int k0 = 0; k0 < 4; ++k0) {
            int k = khalf + k0;
            const float4* p = (const float4*)(hp + k * HSZ);
            float4 a = p[0], bb = p[1];
            sarr[0] += a.x; sarr[1] += a.y; sarr[2] += a.z; sarr[3] += a.w;
            sarr[4] += bb.x; sarr[5] += bb.y; sarr[6] += bb.z; sarr[7] += bb.w;
            bf16x8 v;
            v[0] = (bf16)a.x; v[1] = (bf16)a.y; v[2] = (bf16)a.z; v[3] = (bf16)a.w;
            v[4] = (bf16)bb.x; v[5] = (bf16)bb.y; v[6] = (bf16)bb.z; v[7] = (bf16)bb.w;
            *((bf16x8*)&hs[(node * KCH + k) * LDS_STRIDE + lu * 8]) = v;
        }
        // combine k-halves (lane l <-> l^16)
        #pragma unroll
        for (int i = 0; i < 8; ++i) sarr[i] += __shfl_xor(sarr[i], 16, 64);
        if ((g & 1) == 0) {
            bf16x8 sv;
            #pragma unroll
            for (int i = 0; i < 8; ++i) sv[i] = (bf16)sarr[i];
            *((bf16x8*)&hsum[node * LDS_STRIDE + lu * 8]) = sv;
        }
    }
    __syncthreads();

    // ---- f-gate GEMM: rows split (w2>>2), cols split (w2&3) across 8 waves ----
    f32x4 acc[4][2];
    #pragma unroll
    for (int rt = 0; rt < 4; ++rt)
        #pragma unroll
        for (int cb = 0; cb < 2; ++cb)
            acc[rt][cb] = (f32x4){0.f, 0.f, 0.f, 0.f};

    const int rbase = (w2 >> 2) * 4;    // row-tile base (0 or 4)
    const int cpair = (w2 & 3);         // 32-col group
    const bf16x8* Bf = (const bf16x8*)preUf;
    #pragma unroll
    for (int kb = 0; kb < 4; ++kb) {
        bf16x8 b0 = Bf[((t * 4 + kb) * 8 + cpair * 2 + 0) * 64 + l];
        bf16x8 b1 = Bf[((t * 4 + kb) * 8 + cpair * 2 + 1) * 64 + l];
        #pragma unroll
        for (int rt = 0; rt < 4; ++rt) {
            bf16x8 a = *((const bf16x8*)&hs[((rbase + rt) * 16 + lu) * LDS_STRIDE + kb * 32 + g * 8]);
            acc[rt][0] = __builtin_amdgcn_mfma_f32_16x16x32_bf16(a, b0, acc[rt][0], 0, 0, 0);
            acc[rt][1] = __builtin_amdgcn_mfma_f32_16x16x32_bf16(a, b1, acc[rt][1], 0, 0, 0);
        }
    }

    // ---- iou GEMM: [16, 128] @ U_iou[t] [128, 384]; 3 col-frags per wave ----
    f32x4 acc2[3];
    #pragma unroll
    for (int cf = 0; cf < 3; ++cf) acc2[cf] = (f32x4){0.f, 0.f, 0.f, 0.f};
    const bf16x8* Bi = (const bf16x8*)preUiou;
    #pragma unroll
    for (int kb = 0; kb < 4; ++kb) {
        bf16x8 a = *((const bf16x8*)&hsum[lu * LDS_STRIDE + kb * 32 + g * 8]);
        #pragma unroll
        for (int cf = 0; cf < 3; ++cf) {
            bf16x8 bfr = Bi[((t * 4 + kb) * 24 + w2 * 3 + cf) * 64 + l];
            acc2[cf] = __builtin_amdgcn_mfma_f32_16x16x32_bf16(a, bfr, acc2[cf], 0, 0, 0);
        }
    }
    // iou epilogue: C/D row = g*4 + r, col = (w2*3+cf)*16 + lu
    {
        long gns[4]; bool ok[4];
        #pragma unroll
        for (int r = 0; r < 4; ++r) {
            int m = g * 4 + r;
            ok[r] = m < rem;
            gns[r] = perm[base + (ok[r] ? m : 0)];
        }
        #pragma unroll
        for (int cf = 0; cf < 3; ++cf) {
            int col = (w2 * 3 + cf) * 16 + lu;
            float bi = b_iou[t * 384 + col];
            #pragma unroll
            for (int r = 0; r < 4; ++r)
                if (ok[r]) out[gns[r] * (4 * HSZ) + col] = acc2[cf][r] + bi;
        }
    }

    // ---- write f-gate pre-activations (+b_f) into LDS (bf16), reusing hs ----
    __syncthreads();   // all reads of hs complete
    {
        const int col0 = cpair * 32 + lu;
        const float bf0 = b_f[t * HSZ + col0];
        const float bf1 = b_f[t * HSZ + col0 + 16];
        #pragma unroll
        for (int rt = 0; rt < 4; ++rt) {
            #pragma unroll
            for (int cb = 0; cb < 2; ++cb) {
                #pragma unroll
                for (int r = 0; r < 4; ++r) {
                    int rc = (rbase + rt) * 16 + g * 4 + r;   // = node*8 + k
                    float s = acc[rt][cb][r] + (cb ? bf1 : bf0);
                    hs[rc * LDS_STRIDE + col0 + cb * 16] = (bf16)s;
                }
            }
        }
    }
    __syncthreads();

    // ---- c-reduction: thread owns (node m, 4 cols); coalesced float4 c loads ----
    {
        int m = tid >> 5;            // 0..15
        int cg = tid & 31;           // 0..31 col group of 4
        bool ok = m < rem;
        long gn = perm[base + (ok ? m : 0)];
        const float* crow = c + gn * (long)(KCH * HSZ) + cg * 4;
        float4 fi = *(const float4*)(f_input + gn * HSZ + cg * 4);
        float4 accv = {0.f, 0.f, 0.f, 0.f};
        #pragma unroll
        for (int k = 0; k < KCH; ++k) {
            bf16x4 sv = *(const bf16x4*)&hs[(m * KCH + k) * LDS_STRIDE + cg * 4];
            float4 cv = *(const float4*)(crow + k * HSZ);
            float s0 = (float)sv[0] + fi.x;
            float s1 = (float)sv[1] + fi.y;
            float s2 = (float)sv[2] + fi.z;
            float s3 = (float)sv[3] + fi.w;
            accv.x += cv.x / (1.f + __expf(-s0));
            accv.y += cv.y / (1.f + __expf(-s1));
            accv.z += cv.z / (1.f + __expf(-s2));
            accv.w += cv.w / (1.f + __expf(-s3));
        }
        if (ok) *((float4*)(out + gn * (4 * HSZ) + 3 * HSZ + cg * 4)) = accv;
    }
}

extern "C" void kernel_launch(void* const* d_in, const int* in_sizes, int n_in,
                              void* d_out, int out_size, void* d_ws, size_t ws_size,
                              hipStream_t stream) {
    const float* h       = (const float*)d_in[0];
    const float* c       = (const float*)d_in[1];
    const float* f_input = (const float*)d_in[2];
    const int*   type_id = (const int*)d_in[3];
    const float* U_iou   = (const float*)d_in[4];
    const float* b_iou   = (const float*)d_in[5];
    const float* U_f     = (const float*)d_in[6];
    const float* b_f     = (const float*)d_in[7];
    float* out = (float*)d_out;

    char* ws = (char*)d_ws;
    int* ws_i = (int*)ws;
    int* perm = (int*)(ws + WS_PERM_OFF);
    bf16* preUf = (bf16*)(ws + WS_PREUF_OFF);
    bf16* preUiou = (bf16*)(ws + WS_PREUIOU_OFF);

    hipMemsetAsync(ws, 0, 128, stream);
    k_swz    <<<(T_TYPES * HSZ * HSZ + T_TYPES * HSZ * 3 * HSZ) / 256, 256, 0, stream>>>(U_f, U_iou, preUf, preUiou);
    k_count  <<<N_NODES / 256, 256, 0, stream>>>(type_id, ws_i);
    k_offsets<<<1, 64, 0, stream>>>(ws_i);
    k_scatter<<<N_NODES / 256, 256, 0, stream>>>(type_id, ws_i, perm);

    k_main<<<N_NODES / TM + T_TYPES, 512, 0, stream>>>(h, c, f_input, b_iou, b_f,
                                                       perm, ws_i, preUf, preUiou, out);
}